// Round 14
// baseline (702.865 us; speedup 1.0000x reference)
//
#include <hip/hip_runtime.h>
#include <hip/hip_bf16.h>
#include <cstdint>

// Problem constants
#define BB 2
#define SS 2048
#define HID 2048
#define NH 16
#define NKV 4
#define HD 128
#define SCALE_ 0.08838834764831845f   // 128^-0.5
#define EPS_ 1e-6f

typedef __bf16 bf16;
typedef __attribute__((ext_vector_type(8))) __bf16 bf16x8;
typedef __attribute__((ext_vector_type(4))) __bf16 bf16x4;
typedef __attribute__((ext_vector_type(4))) float f32x4;

__device__ __forceinline__ void g2l16(const bf16* src, void* dst) {
  __builtin_amdgcn_global_load_lds(
      (const __attribute__((address_space(1))) void*)src,
      (__attribute__((address_space(3))) void*)dst, 16, 0, 0);
}

// ---------------- fused f32 -> bf16 convert: wq|wk|wv -> W0 ----------------
__global__ __launch_bounds__(256) void cvt_qkv_k(const float* __restrict__ wq, const float* __restrict__ wk,
                                                 const float* __restrict__ wv, bf16* __restrict__ dst) {
  int i = (blockIdx.x * 256 + threadIdx.x) * 4;
  const float* s;
  if (i < 4194304) s = wq + i;
  else if (i < 5242880) s = wk + (i - 4194304);
  else s = wv + (i - 5242880);
  f32x4 v = *(const f32x4*)s;
  bf16x4 o;
  o[0] = (bf16)v[0]; o[1] = (bf16)v[1]; o[2] = (bf16)v[2]; o[3] = (bf16)v[3];
  *(bf16x4*)(dst + i) = o;
}

// ---------------- fused f32 -> bf16 convert: w1|w3 -> W13 ----------------
__global__ __launch_bounds__(256) void cvt13_k(const float* __restrict__ w1, const float* __restrict__ w3,
                                               bf16* __restrict__ dst) {
  int i = (blockIdx.x * 256 + threadIdx.x) * 4;
  const float* s = (i < 16777216) ? (w1 + i) : (w3 + (i - 16777216));
  f32x4 v = *(const f32x4*)s;
  bf16x4 o;
  o[0] = (bf16)v[0]; o[1] = (bf16)v[1]; o[2] = (bf16)v[2]; o[3] = (bf16)v[3];
  *(bf16x4*)(dst + i) = o;
}

// ---------------- f32 -> bf16 convert ----------------
__global__ __launch_bounds__(256) void cvt_k(const float* __restrict__ src, bf16* __restrict__ dst, int n) {
  int i = (blockIdx.x * 256 + threadIdx.x) * 4;
  if (i >= n) return;
  f32x4 v = *(const f32x4*)(src + i);
  bf16x4 o;
  o[0] = (bf16)v[0]; o[1] = (bf16)v[1]; o[2] = (bf16)v[2]; o[3] = (bf16)v[3];
  *(bf16x4*)(dst + i) = o;
}

// ---------------- RMSNorm: f32 row[2048] -> bf16 ----------------
__global__ __launch_bounds__(256) void rmsnorm_k(const float* __restrict__ X, const float* __restrict__ W,
                                                 bf16* __restrict__ Out) {
  const int row = blockIdx.x;
  const float* xr = X + (size_t)row * 2048;
  const int t = threadIdx.x;
  f32x4 a = *(const f32x4*)(xr + t * 8);
  f32x4 b = *(const f32x4*)(xr + t * 8 + 4);
  float ss = a[0]*a[0] + a[1]*a[1] + a[2]*a[2] + a[3]*a[3]
           + b[0]*b[0] + b[1]*b[1] + b[2]*b[2] + b[3]*b[3];
  #pragma unroll
  for (int m = 1; m <= 32; m <<= 1) ss += __shfl_xor(ss, m);
  __shared__ float red[4];
  if ((t & 63) == 0) red[t >> 6] = ss;
  __syncthreads();
  ss = red[0] + red[1] + red[2] + red[3];
  float sc = rsqrtf(ss * (1.f / 2048.f) + EPS_);
  const float* wp = W + t * 8;
  float v[8] = {a[0], a[1], a[2], a[3], b[0], b[1], b[2], b[3]};
  bf16x8 o;
  #pragma unroll
  for (int j = 0; j < 8; j++) o[j] = (bf16)(v[j] * sc * wp[j]);
  *(bf16x8*)(Out + (size_t)row * 2048 + t * 8) = o;
}

// ---------------- QK-RMSNorm + RoPE (cos/sin computed in-block) ----------------
__global__ __launch_bounds__(256) void qknorm_rope_k(const bf16* __restrict__ QKV,
                                                     const float* __restrict__ QW, const float* __restrict__ KW,
                                                     bf16* __restrict__ Qo, bf16* __restrict__ Ko) {
  const int row = blockIdx.x;          // b*S+s
  const int s = row & (SS - 1);
  const bf16* qr = QKV + (size_t)row * 3072;
  const int t = threadIdx.x;

  __shared__ float cb_s[32], sb_s[32];
  if (t < 32) {
    float inv = powf(10000.f, -(float)t / 32.f);
    float f = (float)s * inv;
    cb_s[t] = cosf(f);
    sb_s[t] = sinf(f);
  }

  bf16x8 qv = *(const bf16x8*)(qr + t * 8);
  float qvf[8];
  float ssq = 0.f, ssk = 0.f;
  #pragma unroll
  for (int j = 0; j < 8; j++) { qvf[j] = (float)qv[j]; ssq += qvf[j] * qvf[j]; }
  float kvf[8];
  if (t < 64) {
    bf16x8 kv = *(const bf16x8*)(qr + 2048 + t * 8);
    #pragma unroll
    for (int j = 0; j < 8; j++) { kvf[j] = (float)kv[j]; ssk += kvf[j] * kvf[j]; }
  }
  #pragma unroll
  for (int m = 1; m <= 32; m <<= 1) { ssq += __shfl_xor(ssq, m); ssk += __shfl_xor(ssk, m); }
  __shared__ float redq[4], redk[4];
  if ((t & 63) == 0) { redq[t >> 6] = ssq; redk[t >> 6] = ssk; }
  __syncthreads();
  ssq = redq[0] + redq[1] + redq[2] + redq[3];
  ssk = redk[0] + redk[1] + redk[2] + redk[3];
  const float scq = rsqrtf(ssq * (1.f / 2048.f) + EPS_);
  const float sck = rsqrtf(ssk * (1.f / 512.f) + EPS_);

  {
    int e = t * 8, dh = e & 127;
    float nv[8];
    #pragma unroll
    for (int j = 0; j < 8; j++) nv[j] = qvf[j] * scq * QW[e + j];
    if (dh < 64) {
      int pe = (dh < 32) ? e + 32 : e - 32;
      bf16x8 pv = *(const bf16x8*)(qr + pe);
      #pragma unroll
      for (int j = 0; j < 8; j++) {
        float pf = (float)pv[j] * scq * QW[pe + j];
        float c = cb_s[(dh + j) & 31], sn = sb_s[(dh + j) & 31];
        nv[j] = (dh < 32) ? (nv[j] * c - pf * sn) : (nv[j] * c + pf * sn);
      }
    }
    bf16x8 o;
    #pragma unroll
    for (int j = 0; j < 8; j++) o[j] = (bf16)nv[j];
    *(bf16x8*)(Qo + (size_t)row * 2048 + e) = o;
  }
  if (t < 64) {
    int e = t * 8, dh = e & 127;
    float nv[8];
    #pragma unroll
    for (int j = 0; j < 8; j++) nv[j] = kvf[j] * sck * KW[e + j];
    if (dh < 64) {
      int pe = (dh < 32) ? e + 32 : e - 32;
      bf16x8 pv = *(const bf16x8*)(qr + 2048 + pe);
      #pragma unroll
      for (int j = 0; j < 8; j++) {
        float pf = (float)pv[j] * sck * KW[pe + j];
        float c = cb_s[(dh + j) & 31], sn = sb_s[(dh + j) & 31];
        nv[j] = (dh < 32) ? (nv[j] * c - pf * sn) : (nv[j] * c + pf * sn);
      }
    }
    bf16x8 o;
    #pragma unroll
    for (int j = 0; j < 8; j++) o[j] = (bf16)nv[j];
    *(bf16x8*)(Ko + (size_t)row * 512 + e) = o;
  }
}

// ---------------- V transpose: qkv v-part -> Vt[B,HK,D,S] ----------------
__global__ __launch_bounds__(256) void vtrans_k(const bf16* __restrict__ QKV, bf16* __restrict__ Vt) {
  const int blk = blockIdx.x;              // B*HK*(S/64) = 256
  const int st = blk & 31, kh = (blk >> 5) & 3, b = blk >> 7;
  const int s0 = st << 6;
  __shared__ __align__(16) bf16 tile[64][136];
  const int t = threadIdx.x;
  {
    const int s = t >> 2, c = (t & 3) * 32;
    const bf16* src = QKV + (size_t)(b * SS + s0 + s) * 3072 + 2560 + kh * 128 + c;
    #pragma unroll
    for (int j = 0; j < 4; j++)
      *(bf16x8*)(&tile[s][c + j * 8]) = *(const bf16x8*)(src + j * 8);
  }
  __syncthreads();
  {
    const int d = t >> 1, sh = (t & 1) * 32;
    bf16* dst = Vt + ((size_t)(b * NKV + kh) * HD + d) * SS + s0 + sh;
    #pragma unroll
    for (int j4 = 0; j4 < 4; j4++) {
      bf16x8 o;
      #pragma unroll
      for (int jj = 0; jj < 8; jj++) o[jj] = tile[sh + j4 * 8 + jj][d];
      *(bf16x8*)(dst + j4 * 8) = o;
    }
  }
}

// ---------------- GEMM: C[M,N] = A[M,K] @ W[N,K]^T (128x128, BK=64) ----------------
// Supertile column-groups-of-8 + XCD swizzle (R9: 5.4x fetch cut); 16x16 MFMA;
// chunk^=(row&7) swizzle; global_load_lds w16.
//  - EPI 0/1/3: double-buffered issue-early/wait-late (64KB LDS, 2 blocks/CU) [R10 win]
//  - EPI 2 (dual): single-buffer 2-barrier (48KB LDS, 3 blocks/CU) [R9 champion; unused this round]
// EPI 0: store bf16.  EPI 1: Cf = resid + acc.  EPI 2: dual-B silu-combine.
// EPI 3: Cb = silu(G)*acc, G read at the same idx (in-place over pass-1 output is safe:
//        each idx is read-then-written exactly once by one thread).
template <int EPI>
__global__ __launch_bounds__(256, 2) void gemm_bt(const bf16* __restrict__ A, const bf16* __restrict__ W0,
                                                  const bf16* __restrict__ W1, bf16* Cb,
                                                  float* __restrict__ Cf, const float* __restrict__ resid,
                                                  const bf16* G,
                                                  int M, int N, int K) {
  constexpr bool DUAL = (EPI == 2);
  constexpr bool DBUF = !DUAL;
  constexpr int TB = DUAL ? 49152 : 32768;
  __shared__ __align__(16) char smem[DBUF ? 2 * TB : TB];

  const int nbm = M >> 7;
  const int nwg = gridDim.x;
  const int per = nwg >> 3;
  const int bid = blockIdx.x;
  const int swz = (bid & 7) * per + (bid >> 3);
  const int gsz = nbm << 3;
  const int g = swz / gsz;
  const int rr = swz - g * gsz;
  const int by = rr >> 3;
  const int bx = (g << 3) + (rr & 7);
  const int m0 = by << 7, n0 = bx << 7;

  const int t = threadIdx.x;
  const int lane = t & 63, wid = t >> 6;
  const int wr = (wid >> 1) * 64, wc = (wid & 1) * 64;
  const int lr = lane & 15, lg = lane >> 4;

  f32x4 acc[4][4], acc3[4][4];
  #pragma unroll
  for (int i = 0; i < 4; i++)
    #pragma unroll
    for (int j = 0; j < 4; j++) {
      acc[i][j] = (f32x4)0.f;
      if constexpr (DUAL) acc3[i][j] = (f32x4)0.f;
    }

  const int srow = t >> 3;
  const int sc8 = t & 7;

  auto stage = [&](int k0, char* base) {
    #pragma unroll
    for (int i = 0; i < 4; i++) {
      int row = i * 32 + srow;
      int csw = sc8 ^ (row & 7);
      g2l16(A + (size_t)(m0 + row) * K + k0 + csw * 8, base + i * 4096 + t * 16);
    }
    #pragma unroll
    for (int i = 0; i < 4; i++) {
      int row = i * 32 + srow;
      int csw = sc8 ^ (row & 7);
      g2l16(W0 + (size_t)(n0 + row) * K + k0 + csw * 8, base + 16384 + i * 4096 + t * 16);
    }
    if constexpr (DUAL) {
      #pragma unroll
      for (int i = 0; i < 4; i++) {
        int row = i * 32 + srow;
        int csw = sc8 ^ (row & 7);
        g2l16(W1 + (size_t)(n0 + row) * K + k0 + csw * 8, base + 32768 + i * 4096 + t * 16);
      }
    }
  };

  auto compute = [&](const char* cur) {
    #pragma unroll
    for (int kk = 0; kk < 2; kk++) {
      bf16x8 af[4];
      #pragma unroll
      for (int mi = 0; mi < 4; mi++) {
        int row = wr + mi * 16 + lr;
        int ch = (kk * 4 + lg) ^ (row & 7);
        af[mi] = *(const bf16x8*)(cur + row * 128 + ch * 16);
      }
      #pragma unroll
      for (int ni = 0; ni < 4; ni++) {
        int rowb = wc + ni * 16 + lr;
        int chb = (kk * 4 + lg) ^ (rowb & 7);
        bf16x8 bb = *(const bf16x8*)(cur + 16384 + rowb * 128 + chb * 16);
        #pragma unroll
        for (int mi = 0; mi < 4; mi++)
          acc[mi][ni] = __builtin_amdgcn_mfma_f32_16x16x32_bf16(af[mi], bb, acc[mi][ni], 0, 0, 0);
        if constexpr (DUAL) {
          bf16x8 b3 = *(const bf16x8*)(cur + 32768 + rowb * 128 + chb * 16);
          #pragma unroll
          for (int mi = 0; mi < 4; mi++)
            acc3[mi][ni] = __builtin_amdgcn_mfma_f32_16x16x32_bf16(af[mi], b3, acc3[mi][ni], 0, 0, 0);
        }
      }
    }
  };

  if constexpr (DBUF) {
    stage(0, smem);
    asm volatile("s_waitcnt vmcnt(0)" ::: "memory");
    __builtin_amdgcn_s_barrier();
    for (int k0 = 0; k0 < K; k0 += 64) {
      char* cur = smem + (((k0 >> 6) & 1) ? TB : 0);
      char* nxt = smem + (((k0 >> 6) & 1) ? 0 : TB);
      if (k0 + 64 < K) stage(k0 + 64, nxt);
      compute(cur);
      asm volatile("s_waitcnt vmcnt(0)" ::: "memory");
      __builtin_amdgcn_s_barrier();
    }
  } else {
    for (int k0 = 0; k0 < K; k0 += 64) {
      __syncthreads();
      stage(k0, smem);
      __syncthreads();
      compute(smem);
    }
  }

  // epilogue: C row = (lane>>4)*4 + r, col = lane&15  [verified m89 layout]
  #pragma unroll
  for (int mi = 0; mi < 4; mi++)
    #pragma unroll
    for (int ni = 0; ni < 4; ni++)
      #pragma unroll
      for (int r = 0; r < 4; r++) {
        int m = m0 + wr + mi * 16 + lg * 4 + r;
        int n = n0 + wc + ni * 16 + lr;
        size_t idx = (size_t)m * N + n;
        if constexpr (EPI == 0) {
          Cb[idx] = (bf16)acc[mi][ni][r];
        } else if constexpr (EPI == 1) {
          Cf[idx] = resid[idx] + acc[mi][ni][r];
        } else if constexpr (EPI == 3) {
          float g_ = (float)G[idx], u = acc[mi][ni][r];
          Cb[idx] = (bf16)(g_ * u / (1.f + __expf(-g_)));
        } else {
          float g_ = acc[mi][ni][r], u = acc3[mi][ni][r];
          Cb[idx] = (bf16)(g_ * u / (1.f + __expf(-g_)));
        }
      }
}

// ---------------- Sliding-window GQA flash attention ----------------
__global__ __launch_bounds__(256, 2) void attn_kernel(const bf16* __restrict__ Q, const bf16* __restrict__ Kr,
                                                      const bf16* __restrict__ Vt, bf16* __restrict__ O) {
  __shared__ __align__(16) char smem[41984];   // 16K K + 16K V + 4*2304 P
  const int qt = blockIdx.x, h = blockIdx.y, b = blockIdx.z;
  const int kh = h >> 2;
  const int q0 = qt << 6;
  const int t = threadIdx.x, lane = t & 63, wid = t >> 6;
  const int lr = lane & 15, lg = lane >> 4;

  bf16x8 qf[4];
  {
    const bf16* qb = Q + (((size_t)b * SS + q0 + wid * 16 + lr) * NH + h) * HD;
    #pragma unroll
    for (int c = 0; c < 4; c++) qf[c] = *(const bf16x8*)(qb + c * 32 + lg * 8);
  }
  f32x4 of[8];
  #pragma unroll
  for (int i = 0; i < 8; i++) of[i] = (f32x4)0.f;
  float m_[4] = {-1e30f, -1e30f, -1e30f, -1e30f};
  float l_[4] = {0.f, 0.f, 0.f, 0.f};

  const int kt_lo = qt >= 8 ? qt - 8 : 0;
  for (int kt = kt_lo; kt <= qt; kt++) {
    const int k0 = kt << 6;
    __syncthreads();
    {
      int rb = t >> 4, c = t & 15;
      #pragma unroll
      for (int i = 0; i < 4; i++) {
        int r = i * 16 + rb;
        int csw = c ^ (r & 7);
        g2l16(Kr + (((size_t)b * SS + k0 + r) * NKV + kh) * HD + csw * 8, smem + i * 4096 + t * 16);
      }
    }
    {
      int rb = t >> 3, c = t & 7;
      #pragma unroll
      for (int i = 0; i < 4; i++) {
        int r = i * 32 + rb;
        int csw = c ^ (r & 7);
        g2l16(Vt + ((size_t)(b * NKV + kh) * HD + r) * SS + k0 + csw * 8, smem + 16384 + i * 4096 + t * 16);
      }
    }
    __syncthreads();

    f32x4 sf[4];
    #pragma unroll
    for (int nt = 0; nt < 4; nt++) {
      sf[nt] = (f32x4)0.f;
      #pragma unroll
      for (int c = 0; c < 4; c++) {
        int row = nt * 16 + lr;
        int ch = (c * 4 + lg) ^ (row & 7);
        bf16x8 kf = *(const bf16x8*)(smem + row * 256 + ch * 16);
        sf[nt] = __builtin_amdgcn_mfma_f32_16x16x32_bf16(qf[c], kf, sf[nt], 0, 0, 0);
      }
    }
    #pragma unroll
    for (int r = 0; r < 4; r++) {
      int q = q0 + wid * 16 + lg * 4 + r;
      float mx = -1e30f;
      #pragma unroll
      for (int nt = 0; nt < 4; nt++) {
        int k = k0 + nt * 16 + lr;
        float s = sf[nt][r] * SCALE_;
        s = (k <= q && k + 512 >= q) ? s : -1e30f;
        sf[nt][r] = s;
        mx = fmaxf(mx, s);
      }
      mx = fmaxf(mx, __shfl_xor(mx, 1));
      mx = fmaxf(mx, __shfl_xor(mx, 2));
      mx = fmaxf(mx, __shfl_xor(mx, 4));
      mx = fmaxf(mx, __shfl_xor(mx, 8));
      float mnew = fmaxf(m_[r], mx);
      float corr = __expf(m_[r] - mnew);
      float rs = 0.f;
      #pragma unroll
      for (int nt = 0; nt < 4; nt++) {
        float p = __expf(sf[nt][r] - mnew);
        sf[nt][r] = p;
        rs += p;
      }
      rs += __shfl_xor(rs, 1); rs += __shfl_xor(rs, 2);
      rs += __shfl_xor(rs, 4); rs += __shfl_xor(rs, 8);
      l_[r] = l_[r] * corr + rs;
      m_[r] = mnew;
      #pragma unroll
      for (int dt = 0; dt < 8; dt++) of[dt][r] *= corr;
    }
    bf16* Pl = (bf16*)(smem + 32768 + wid * 2304);
    #pragma unroll
    for (int nt = 0; nt < 4; nt++)
      #pragma unroll
      for (int r = 0; r < 4; r++)
        Pl[(lg * 4 + r) * 72 + nt * 16 + lr] = (bf16)sf[nt][r];
    bf16x8 pf[2];
    #pragma unroll
    for (int c = 0; c < 2; c++) pf[c] = *(const bf16x8*)(Pl + lr * 72 + c * 32 + lg * 8);
    #pragma unroll
    for (int dt = 0; dt < 8; dt++) {
      #pragma unroll
      for (int c = 0; c < 2; c++) {
        int row = dt * 16 + lr;
        int ch = (c * 4 + lg) ^ (row & 7);
        bf16x8 vf = *(const bf16x8*)(smem + 16384 + row * 128 + ch * 16);
        of[dt] = __builtin_amdgcn_mfma_f32_16x16x32_bf16(pf[c], vf, of[dt], 0, 0, 0);
      }
    }
  }
  #pragma unroll
  for (int dt = 0; dt < 8; dt++)
    #pragma unroll
    for (int r = 0; r < 4; r++) {
      int q = q0 + wid * 16 + lg * 4 + r;
      O[(((size_t)b * SS + q) * NH + h) * HD + dt * 16 + lr] = (bf16)(of[dt][r] / l_[r]);
    }
}

// ---------------- launch ----------------
extern "C" void kernel_launch(void* const* d_in, const int* in_sizes, int n_in,
                              void* d_out, int out_size, void* d_ws, size_t ws_size,
                              hipStream_t stream) {
  (void)in_sizes; (void)n_in; (void)out_size; (void)ws_size;
  const float* x   = (const float*)d_in[0];
  const float* wq  = (const float*)d_in[1];
  const float* wk  = (const float*)d_in[2];
  const float* wv  = (const float*)d_in[3];
  const float* wo  = (const float*)d_in[4];
  const float* qnw = (const float*)d_in[5];
  const float* knw = (const float*)d_in[6];
  const float* ln1 = (const float*)d_in[7];
  const float* ln2 = (const float*)d_in[8];
  const float* w1  = (const float*)d_in[9];
  const float* w2  = (const float*)d_in[10];
  const float* w3  = (const float*)d_in[11];
  float* out = (float*)d_out;
  char* ws = (char*)d_ws;

  bf16* W0  = (bf16*)(ws + 0);            // wqkv bf16 -> wo -> w1|w3 -> w2
  bf16* QKV = (bf16*)(ws + 12582912);     // [4096,3072] bf16
  bf16* QRO = (bf16*)(ws + 37748736);     // [4096,2048] bf16
  bf16* KRO = (bf16*)(ws + 54525952);     // [4096,512] bf16
  bf16* ATT = (bf16*)(ws + 58720256);     // [4096,2048] bf16
  bf16* VT  = (bf16*)(ws + 75497472);     // [B,HK,D,S] bf16
  bf16* HBF = (bf16*)(ws + 79691776);     // [4096,2048] bf16 (ln1 out, later ln2 out)
  bf16* ACT = (bf16*)(ws + 96468992);     // [4096,8192] bf16 (g then silu(g)*u in place)
  bf16* W13 = (bf16*)ws;                  // w1 then w3, after region A is dead
  bf16* W2B = (bf16*)ws;                  // w2, after SwiGLU gemms

  cvt_qkv_k<<<6144, 256, 0, stream>>>(wq, wk, wv, W0);
  rmsnorm_k<<<4096, 256, 0, stream>>>(x, ln1, HBF);
  gemm_bt<0><<<768, 256, 0, stream>>>(HBF, W0, nullptr, QKV, nullptr, nullptr, nullptr, 4096, 3072, 2048);
  qknorm_rope_k<<<4096, 256, 0, stream>>>(QKV, qnw, knw, QRO, KRO);
  vtrans_k<<<256, 256, 0, stream>>>(QKV, VT);
  cvt_k<<<4096, 256, 0, stream>>>(wo, W0, 4194304);     // overwrites wqkv (dead)
  attn_kernel<<<dim3(32, 16, 2), 256, 0, stream>>>(QRO, KRO, VT, ATT);
  gemm_bt<1><<<512, 256, 0, stream>>>(ATT, W0, nullptr, nullptr, out, x, nullptr, 4096, 2048, 2048);
  rmsnorm_k<<<4096, 256, 0, stream>>>(out, ln2, HBF);
  cvt13_k<<<32768, 256, 0, stream>>>(w1, w3, W13);      // region A dead now
  gemm_bt<0><<<2048, 256, 0, stream>>>(HBF, W13, nullptr, ACT, nullptr, nullptr, nullptr, 4096, 8192, 2048);               // g
  gemm_bt<3><<<2048, 256, 0, stream>>>(HBF, W13 + 16777216, nullptr, ACT, nullptr, nullptr, ACT, 4096, 8192, 2048);        // silu(g)*u
  cvt_k<<<16384, 256, 0, stream>>>(w2, W2B, 16777216);
  gemm_bt<1><<<512, 256, 0, stream>>>(ACT, W2B, nullptr, nullptr, out, out, nullptr, 4096, 2048, 8192);
}

// Round 15
// 619.258 us; speedup vs baseline: 1.1350x; 1.1350x over previous
//
#include <hip/hip_runtime.h>
#include <hip/hip_bf16.h>
#include <cstdint>

// Problem constants
#define BB 2
#define SS 2048
#define HID 2048
#define NH 16
#define NKV 4
#define HD 128
#define SCALE_ 0.08838834764831845f   // 128^-0.5
#define EPS_ 1e-6f

typedef __bf16 bf16;
typedef __attribute__((ext_vector_type(8))) __bf16 bf16x8;
typedef __attribute__((ext_vector_type(4))) __bf16 bf16x4;
typedef __attribute__((ext_vector_type(4))) float f32x4;

__device__ __forceinline__ void g2l16(const bf16* src, void* dst) {
  __builtin_amdgcn_global_load_lds(
      (const __attribute__((address_space(1))) void*)src,
      (__attribute__((address_space(3))) void*)dst, 16, 0, 0);
}

// ---------------- fused f32 -> bf16 convert: wq|wk|wv -> W0 ----------------
__global__ __launch_bounds__(256) void cvt_qkv_k(const float* __restrict__ wq, const float* __restrict__ wk,
                                                 const float* __restrict__ wv, bf16* __restrict__ dst) {
  int i = (blockIdx.x * 256 + threadIdx.x) * 4;
  const float* s;
  if (i < 4194304) s = wq + i;
  else if (i < 5242880) s = wk + (i - 4194304);
  else s = wv + (i - 5242880);
  f32x4 v = *(const f32x4*)s;
  bf16x4 o;
  o[0] = (bf16)v[0]; o[1] = (bf16)v[1]; o[2] = (bf16)v[2]; o[3] = (bf16)v[3];
  *(bf16x4*)(dst + i) = o;
}

// ---------------- fused f32 -> bf16 convert: w1|w3 -> W13 ----------------
__global__ __launch_bounds__(256) void cvt13_k(const float* __restrict__ w1, const float* __restrict__ w3,
                                               bf16* __restrict__ dst) {
  int i = (blockIdx.x * 256 + threadIdx.x) * 4;
  const float* s = (i < 16777216) ? (w1 + i) : (w3 + (i - 16777216));
  f32x4 v = *(const f32x4*)s;
  bf16x4 o;
  o[0] = (bf16)v[0]; o[1] = (bf16)v[1]; o[2] = (bf16)v[2]; o[3] = (bf16)v[3];
  *(bf16x4*)(dst + i) = o;
}

// ---------------- f32 -> bf16 convert ----------------
__global__ __launch_bounds__(256) void cvt_k(const float* __restrict__ src, bf16* __restrict__ dst, int n) {
  int i = (blockIdx.x * 256 + threadIdx.x) * 4;
  if (i >= n) return;
  f32x4 v = *(const f32x4*)(src + i);
  bf16x4 o;
  o[0] = (bf16)v[0]; o[1] = (bf16)v[1]; o[2] = (bf16)v[2]; o[3] = (bf16)v[3];
  *(bf16x4*)(dst + i) = o;
}

// ---------------- RMSNorm: f32 row[2048] -> bf16 ----------------
__global__ __launch_bounds__(256) void rmsnorm_k(const float* __restrict__ X, const float* __restrict__ W,
                                                 bf16* __restrict__ Out) {
  const int row = blockIdx.x;
  const float* xr = X + (size_t)row * 2048;
  const int t = threadIdx.x;
  f32x4 a = *(const f32x4*)(xr + t * 8);
  f32x4 b = *(const f32x4*)(xr + t * 8 + 4);
  float ss = a[0]*a[0] + a[1]*a[1] + a[2]*a[2] + a[3]*a[3]
           + b[0]*b[0] + b[1]*b[1] + b[2]*b[2] + b[3]*b[3];
  #pragma unroll
  for (int m = 1; m <= 32; m <<= 1) ss += __shfl_xor(ss, m);
  __shared__ float red[4];
  if ((t & 63) == 0) red[t >> 6] = ss;
  __syncthreads();
  ss = red[0] + red[1] + red[2] + red[3];
  float sc = rsqrtf(ss * (1.f / 2048.f) + EPS_);
  const float* wp = W + t * 8;
  float v[8] = {a[0], a[1], a[2], a[3], b[0], b[1], b[2], b[3]};
  bf16x8 o;
  #pragma unroll
  for (int j = 0; j < 8; j++) o[j] = (bf16)(v[j] * sc * wp[j]);
  *(bf16x8*)(Out + (size_t)row * 2048 + t * 8) = o;
}

// ---------------- QK-RMSNorm + RoPE (cos/sin computed in-block) ----------------
__global__ __launch_bounds__(256) void qknorm_rope_k(const bf16* __restrict__ QKV,
                                                     const float* __restrict__ QW, const float* __restrict__ KW,
                                                     bf16* __restrict__ Qo, bf16* __restrict__ Ko) {
  const int row = blockIdx.x;          // b*S+s
  const int s = row & (SS - 1);
  const bf16* qr = QKV + (size_t)row * 3072;
  const int t = threadIdx.x;

  __shared__ float cb_s[32], sb_s[32];
  if (t < 32) {
    float inv = powf(10000.f, -(float)t / 32.f);
    float f = (float)s * inv;
    cb_s[t] = cosf(f);
    sb_s[t] = sinf(f);
  }

  bf16x8 qv = *(const bf16x8*)(qr + t * 8);
  float qvf[8];
  float ssq = 0.f, ssk = 0.f;
  #pragma unroll
  for (int j = 0; j < 8; j++) { qvf[j] = (float)qv[j]; ssq += qvf[j] * qvf[j]; }
  float kvf[8];
  if (t < 64) {
    bf16x8 kv = *(const bf16x8*)(qr + 2048 + t * 8);
    #pragma unroll
    for (int j = 0; j < 8; j++) { kvf[j] = (float)kv[j]; ssk += kvf[j] * kvf[j]; }
  }
  #pragma unroll
  for (int m = 1; m <= 32; m <<= 1) { ssq += __shfl_xor(ssq, m); ssk += __shfl_xor(ssk, m); }
  __shared__ float redq[4], redk[4];
  if ((t & 63) == 0) { redq[t >> 6] = ssq; redk[t >> 6] = ssk; }
  __syncthreads();
  ssq = redq[0] + redq[1] + redq[2] + redq[3];
  ssk = redk[0] + redk[1] + redk[2] + redk[3];
  const float scq = rsqrtf(ssq * (1.f / 2048.f) + EPS_);
  const float sck = rsqrtf(ssk * (1.f / 512.f) + EPS_);

  {
    int e = t * 8, dh = e & 127;
    float nv[8];
    #pragma unroll
    for (int j = 0; j < 8; j++) nv[j] = qvf[j] * scq * QW[e + j];
    if (dh < 64) {
      int pe = (dh < 32) ? e + 32 : e - 32;
      bf16x8 pv = *(const bf16x8*)(qr + pe);
      #pragma unroll
      for (int j = 0; j < 8; j++) {
        float pf = (float)pv[j] * scq * QW[pe + j];
        float c = cb_s[(dh + j) & 31], sn = sb_s[(dh + j) & 31];
        nv[j] = (dh < 32) ? (nv[j] * c - pf * sn) : (nv[j] * c + pf * sn);
      }
    }
    bf16x8 o;
    #pragma unroll
    for (int j = 0; j < 8; j++) o[j] = (bf16)nv[j];
    *(bf16x8*)(Qo + (size_t)row * 2048 + e) = o;
  }
  if (t < 64) {
    int e = t * 8, dh = e & 127;
    float nv[8];
    #pragma unroll
    for (int j = 0; j < 8; j++) nv[j] = kvf[j] * sck * KW[e + j];
    if (dh < 64) {
      int pe = (dh < 32) ? e + 32 : e - 32;
      bf16x8 pv = *(const bf16x8*)(qr + 2048 + pe);
      #pragma unroll
      for (int j = 0; j < 8; j++) {
        float pf = (float)pv[j] * sck * KW[pe + j];
        float c = cb_s[(dh + j) & 31], sn = sb_s[(dh + j) & 31];
        nv[j] = (dh < 32) ? (nv[j] * c - pf * sn) : (nv[j] * c + pf * sn);
      }
    }
    bf16x8 o;
    #pragma unroll
    for (int j = 0; j < 8; j++) o[j] = (bf16)nv[j];
    *(bf16x8*)(Ko + (size_t)row * 512 + e) = o;
  }
}

// ---------------- V transpose: qkv v-part -> Vt[B,HK,D,S] ----------------
__global__ __launch_bounds__(256) void vtrans_k(const bf16* __restrict__ QKV, bf16* __restrict__ Vt) {
  const int blk = blockIdx.x;              // B*HK*(S/64) = 256
  const int st = blk & 31, kh = (blk >> 5) & 3, b = blk >> 7;
  const int s0 = st << 6;
  __shared__ __align__(16) bf16 tile[64][136];
  const int t = threadIdx.x;
  {
    const int s = t >> 2, c = (t & 3) * 32;
    const bf16* src = QKV + (size_t)(b * SS + s0 + s) * 3072 + 2560 + kh * 128 + c;
    #pragma unroll
    for (int j = 0; j < 4; j++)
      *(bf16x8*)(&tile[s][c + j * 8]) = *(const bf16x8*)(src + j * 8);
  }
  __syncthreads();
  {
    const int d = t >> 1, sh = (t & 1) * 32;
    bf16* dst = Vt + ((size_t)(b * NKV + kh) * HD + d) * SS + s0 + sh;
    #pragma unroll
    for (int j4 = 0; j4 < 4; j4++) {
      bf16x8 o;
      #pragma unroll
      for (int jj = 0; jj < 8; jj++) o[jj] = tile[sh + j4 * 8 + jj][d];
      *(bf16x8*)(dst + j4 * 8) = o;
    }
  }
}

// ---------------- GEMM: C[M,N] = A[M,K] @ W[N,K]^T (128x128, BK=64) ----------------
// Supertile column-groups-of-8 + XCD swizzle (R9: 5.4x fetch cut); 16x16 MFMA;
// chunk^=(row&7) swizzle; global_load_lds w16.
//  - non-dual (EPI 0/1): double-buffered issue-early/wait-late (64KB LDS, 2 blocks/CU) [R10 win]
//  - dual (EPI 2): single-buffer 2-barrier (48KB LDS, 3 blocks/CU) [R9 champion: 241us/1141TF.
//    A-reuse across two B-matrices beats split passes (R14: 2x190us) and every deeper pipeline
//    (R3/5/6/10/12) lost via the occupancy cliff.]
// EPI 0: store bf16.  EPI 1: Cf = resid + acc.  EPI 2: dual-B, Cb = silu(accW0)*accW1.
template <int EPI>
__global__ __launch_bounds__(256, 2) void gemm_bt(const bf16* __restrict__ A, const bf16* __restrict__ W0,
                                                  const bf16* __restrict__ W1, bf16* __restrict__ Cb,
                                                  float* __restrict__ Cf, const float* __restrict__ resid,
                                                  int M, int N, int K) {
  constexpr bool DUAL = (EPI == 2);
  constexpr bool DBUF = !DUAL;
  constexpr int TB = DUAL ? 49152 : 32768;
  __shared__ __align__(16) char smem[DBUF ? 2 * TB : TB];

  const int nbm = M >> 7;
  const int nwg = gridDim.x;
  const int per = nwg >> 3;
  const int bid = blockIdx.x;
  const int swz = (bid & 7) * per + (bid >> 3);
  const int gsz = nbm << 3;
  const int g = swz / gsz;
  const int rr = swz - g * gsz;
  const int by = rr >> 3;
  const int bx = (g << 3) + (rr & 7);
  const int m0 = by << 7, n0 = bx << 7;

  const int t = threadIdx.x;
  const int lane = t & 63, wid = t >> 6;
  const int wr = (wid >> 1) * 64, wc = (wid & 1) * 64;
  const int lr = lane & 15, lg = lane >> 4;

  f32x4 acc[4][4], acc3[4][4];
  #pragma unroll
  for (int i = 0; i < 4; i++)
    #pragma unroll
    for (int j = 0; j < 4; j++) {
      acc[i][j] = (f32x4)0.f;
      if constexpr (DUAL) acc3[i][j] = (f32x4)0.f;
    }

  const int srow = t >> 3;
  const int sc8 = t & 7;

  auto stage = [&](int k0, char* base) {
    #pragma unroll
    for (int i = 0; i < 4; i++) {
      int row = i * 32 + srow;
      int csw = sc8 ^ (row & 7);
      g2l16(A + (size_t)(m0 + row) * K + k0 + csw * 8, base + i * 4096 + t * 16);
    }
    #pragma unroll
    for (int i = 0; i < 4; i++) {
      int row = i * 32 + srow;
      int csw = sc8 ^ (row & 7);
      g2l16(W0 + (size_t)(n0 + row) * K + k0 + csw * 8, base + 16384 + i * 4096 + t * 16);
    }
    if constexpr (DUAL) {
      #pragma unroll
      for (int i = 0; i < 4; i++) {
        int row = i * 32 + srow;
        int csw = sc8 ^ (row & 7);
        g2l16(W1 + (size_t)(n0 + row) * K + k0 + csw * 8, base + 32768 + i * 4096 + t * 16);
      }
    }
  };

  auto compute = [&](const char* cur) {
    #pragma unroll
    for (int kk = 0; kk < 2; kk++) {
      bf16x8 af[4];
      #pragma unroll
      for (int mi = 0; mi < 4; mi++) {
        int row = wr + mi * 16 + lr;
        int ch = (kk * 4 + lg) ^ (row & 7);
        af[mi] = *(const bf16x8*)(cur + row * 128 + ch * 16);
      }
      #pragma unroll
      for (int ni = 0; ni < 4; ni++) {
        int rowb = wc + ni * 16 + lr;
        int chb = (kk * 4 + lg) ^ (rowb & 7);
        bf16x8 bb = *(const bf16x8*)(cur + 16384 + rowb * 128 + chb * 16);
        #pragma unroll
        for (int mi = 0; mi < 4; mi++)
          acc[mi][ni] = __builtin_amdgcn_mfma_f32_16x16x32_bf16(af[mi], bb, acc[mi][ni], 0, 0, 0);
        if constexpr (DUAL) {
          bf16x8 b3 = *(const bf16x8*)(cur + 32768 + rowb * 128 + chb * 16);
          #pragma unroll
          for (int mi = 0; mi < 4; mi++)
            acc3[mi][ni] = __builtin_amdgcn_mfma_f32_16x16x32_bf16(af[mi], b3, acc3[mi][ni], 0, 0, 0);
        }
      }
    }
  };

  if constexpr (DBUF) {
    stage(0, smem);
    asm volatile("s_waitcnt vmcnt(0)" ::: "memory");
    __builtin_amdgcn_s_barrier();
    for (int k0 = 0; k0 < K; k0 += 64) {
      char* cur = smem + (((k0 >> 6) & 1) ? TB : 0);
      char* nxt = smem + (((k0 >> 6) & 1) ? 0 : TB);
      if (k0 + 64 < K) stage(k0 + 64, nxt);
      compute(cur);
      asm volatile("s_waitcnt vmcnt(0)" ::: "memory");
      __builtin_amdgcn_s_barrier();
    }
  } else {
    for (int k0 = 0; k0 < K; k0 += 64) {
      __syncthreads();
      stage(k0, smem);
      __syncthreads();
      compute(smem);
    }
  }

  // epilogue: C row = (lane>>4)*4 + r, col = lane&15  [verified m89 layout]
  #pragma unroll
  for (int mi = 0; mi < 4; mi++)
    #pragma unroll
    for (int ni = 0; ni < 4; ni++)
      #pragma unroll
      for (int r = 0; r < 4; r++) {
        int m = m0 + wr + mi * 16 + lg * 4 + r;
        int n = n0 + wc + ni * 16 + lr;
        size_t idx = (size_t)m * N + n;
        if constexpr (EPI == 0) {
          Cb[idx] = (bf16)acc[mi][ni][r];
        } else if constexpr (EPI == 1) {
          Cf[idx] = resid[idx] + acc[mi][ni][r];
        } else {
          float g_ = acc[mi][ni][r], u = acc3[mi][ni][r];
          Cb[idx] = (bf16)(g_ * u / (1.f + __expf(-g_)));
        }
      }
}

// ---------------- Sliding-window GQA flash attention ----------------
__global__ __launch_bounds__(256, 2) void attn_kernel(const bf16* __restrict__ Q, const bf16* __restrict__ Kr,
                                                      const bf16* __restrict__ Vt, bf16* __restrict__ O) {
  __shared__ __align__(16) char smem[41984];   // 16K K + 16K V + 4*2304 P
  const int qt = blockIdx.x, h = blockIdx.y, b = blockIdx.z;
  const int kh = h >> 2;
  const int q0 = qt << 6;
  const int t = threadIdx.x, lane = t & 63, wid = t >> 6;
  const int lr = lane & 15, lg = lane >> 4;

  bf16x8 qf[4];
  {
    const bf16* qb = Q + (((size_t)b * SS + q0 + wid * 16 + lr) * NH + h) * HD;
    #pragma unroll
    for (int c = 0; c < 4; c++) qf[c] = *(const bf16x8*)(qb + c * 32 + lg * 8);
  }
  f32x4 of[8];
  #pragma unroll
  for (int i = 0; i < 8; i++) of[i] = (f32x4)0.f;
  float m_[4] = {-1e30f, -1e30f, -1e30f, -1e30f};
  float l_[4] = {0.f, 0.f, 0.f, 0.f};

  const int kt_lo = qt >= 8 ? qt - 8 : 0;
  for (int kt = kt_lo; kt <= qt; kt++) {
    const int k0 = kt << 6;
    __syncthreads();
    {
      int rb = t >> 4, c = t & 15;
      #pragma unroll
      for (int i = 0; i < 4; i++) {
        int r = i * 16 + rb;
        int csw = c ^ (r & 7);
        g2l16(Kr + (((size_t)b * SS + k0 + r) * NKV + kh) * HD + csw * 8, smem + i * 4096 + t * 16);
      }
    }
    {
      int rb = t >> 3, c = t & 7;
      #pragma unroll
      for (int i = 0; i < 4; i++) {
        int r = i * 32 + rb;
        int csw = c ^ (r & 7);
        g2l16(Vt + ((size_t)(b * NKV + kh) * HD + r) * SS + k0 + csw * 8, smem + 16384 + i * 4096 + t * 16);
      }
    }
    __syncthreads();

    f32x4 sf[4];
    #pragma unroll
    for (int nt = 0; nt < 4; nt++) {
      sf[nt] = (f32x4)0.f;
      #pragma unroll
      for (int c = 0; c < 4; c++) {
        int row = nt * 16 + lr;
        int ch = (c * 4 + lg) ^ (row & 7);
        bf16x8 kf = *(const bf16x8*)(smem + row * 256 + ch * 16);
        sf[nt] = __builtin_amdgcn_mfma_f32_16x16x32_bf16(qf[c], kf, sf[nt], 0, 0, 0);
      }
    }
    #pragma unroll
    for (int r = 0; r < 4; r++) {
      int q = q0 + wid * 16 + lg * 4 + r;
      float mx = -1e30f;
      #pragma unroll
      for (int nt = 0; nt < 4; nt++) {
        int k = k0 + nt * 16 + lr;
        float s = sf[nt][r] * SCALE_;
        s = (k <= q && k + 512 >= q) ? s : -1e30f;
        sf[nt][r] = s;
        mx = fmaxf(mx, s);
      }
      mx = fmaxf(mx, __shfl_xor(mx, 1));
      mx = fmaxf(mx, __shfl_xor(mx, 2));
      mx = fmaxf(mx, __shfl_xor(mx, 4));
      mx = fmaxf(mx, __shfl_xor(mx, 8));
      float mnew = fmaxf(m_[r], mx);
      float corr = __expf(m_[r] - mnew);
      float rs = 0.f;
      #pragma unroll
      for (int nt = 0; nt < 4; nt++) {
        float p = __expf(sf[nt][r] - mnew);
        sf[nt][r] = p;
        rs += p;
      }
      rs += __shfl_xor(rs, 1); rs += __shfl_xor(rs, 2);
      rs += __shfl_xor(rs, 4); rs += __shfl_xor(rs, 8);
      l_[r] = l_[r] * corr + rs;
      m_[r] = mnew;
      #pragma unroll
      for (int dt = 0; dt < 8; dt++) of[dt][r] *= corr;
    }
    bf16* Pl = (bf16*)(smem + 32768 + wid * 2304);
    #pragma unroll
    for (int nt = 0; nt < 4; nt++)
      #pragma unroll
      for (int r = 0; r < 4; r++)
        Pl[(lg * 4 + r) * 72 + nt * 16 + lr] = (bf16)sf[nt][r];
    bf16x8 pf[2];
    #pragma unroll
    for (int c = 0; c < 2; c++) pf[c] = *(const bf16x8*)(Pl + lr * 72 + c * 32 + lg * 8);
    #pragma unroll
    for (int dt = 0; dt < 8; dt++) {
      #pragma unroll
      for (int c = 0; c < 2; c++) {
        int row = dt * 16 + lr;
        int ch = (c * 4 + lg) ^ (row & 7);
        bf16x8 vf = *(const bf16x8*)(smem + 16384 + row * 128 + ch * 16);
        of[dt] = __builtin_amdgcn_mfma_f32_16x16x32_bf16(pf[c], vf, of[dt], 0, 0, 0);
      }
    }
  }
  #pragma unroll
  for (int dt = 0; dt < 8; dt++)
    #pragma unroll
    for (int r = 0; r < 4; r++) {
      int q = q0 + wid * 16 + lg * 4 + r;
      O[(((size_t)b * SS + q) * NH + h) * HD + dt * 16 + lr] = (bf16)(of[dt][r] / l_[r]);
    }
}

// ---------------- launch ----------------
extern "C" void kernel_launch(void* const* d_in, const int* in_sizes, int n_in,
                              void* d_out, int out_size, void* d_ws, size_t ws_size,
                              hipStream_t stream) {
  (void)in_sizes; (void)n_in; (void)out_size; (void)ws_size;
  const float* x   = (const float*)d_in[0];
  const float* wq  = (const float*)d_in[1];
  const float* wk  = (const float*)d_in[2];
  const float* wv  = (const float*)d_in[3];
  const float* wo  = (const float*)d_in[4];
  const float* qnw = (const float*)d_in[5];
  const float* knw = (const float*)d_in[6];
  const float* ln1 = (const float*)d_in[7];
  const float* ln2 = (const float*)d_in[8];
  const float* w1  = (const float*)d_in[9];
  const float* w2  = (const float*)d_in[10];
  const float* w3  = (const float*)d_in[11];
  float* out = (float*)d_out;
  char* ws = (char*)d_ws;

  // workspace layout (region A reused across phases; all reads precede overwrites in stream order)
  bf16* W0  = (bf16*)(ws + 0);            // wqkv bf16 [3072,2048] -> wo -> w1|w3 -> w2
  bf16* QKV = (bf16*)(ws + 12582912);     // [4096,3072] bf16
  bf16* QRO = (bf16*)(ws + 37748736);     // [4096,2048] bf16
  bf16* KRO = (bf16*)(ws + 54525952);     // [4096,512] bf16
  bf16* ATT = (bf16*)(ws + 58720256);     // [4096,2048] bf16
  bf16* VT  = (bf16*)(ws + 75497472);     // [B,HK,D,S] bf16
  bf16* HBF = (bf16*)(ws + 79691776);     // [4096,2048] bf16 (ln1 out, later ln2 out)
  bf16* ACT = (bf16*)(ws + 96468992);     // [4096,8192] bf16
  bf16* W13 = (bf16*)ws;                  // w1 then w3, after region A is dead
  bf16* W2B = (bf16*)ws;                  // w2, after dual gemm

  cvt_qkv_k<<<6144, 256, 0, stream>>>(wq, wk, wv, W0);
  rmsnorm_k<<<4096, 256, 0, stream>>>(x, ln1, HBF);
  gemm_bt<0><<<768, 256, 0, stream>>>(HBF, W0, nullptr, QKV, nullptr, nullptr, 4096, 3072, 2048);
  qknorm_rope_k<<<4096, 256, 0, stream>>>(QKV, qnw, knw, QRO, KRO);
  vtrans_k<<<256, 256, 0, stream>>>(QKV, VT);
  cvt_k<<<4096, 256, 0, stream>>>(wo, W0, 4194304);     // overwrites wqkv (dead)
  attn_kernel<<<dim3(32, 16, 2), 256, 0, stream>>>(QRO, KRO, VT, ATT);
  gemm_bt<1><<<512, 256, 0, stream>>>(ATT, W0, nullptr, nullptr, out, x, 4096, 2048, 2048);
  rmsnorm_k<<<4096, 256, 0, stream>>>(out, ln2, HBF);
  cvt13_k<<<32768, 256, 0, stream>>>(w1, w3, W13);      // region A dead now
  gemm_bt<2><<<2048, 256, 0, stream>>>(HBF, W13, W13 + 16777216, ACT, nullptr, nullptr, 4096, 8192, 2048);
  cvt_k<<<16384, 256, 0, stream>>>(w2, W2B, 16777216);
  gemm_bt<1><<<512, 256, 0, stream>>>(ACT, W2B, nullptr, nullptr, out, out, 4096, 2048, 8192);
}